// Round 2
// baseline (2435.695 us; speedup 1.0000x reference)
//
#include <hip/hip_runtime.h>
#include <math.h>

// Problem constants
#define M_TOTAL 32768   // B*T = 16*2048
#define D_DIM   1024
#define K_DIM   2048

// d_out flat layout (float32 elements)
#define OUT0_OFF 0ULL           // quantized   [32768,1024]
#define OUT1_OFF 33554432ULL    // quant_loss  [32768,2048] (also used as S scratch)
#define OUT2_OFF 100663296ULL   // nn_idx      [32768] (written as float)
#define OUT3_OFF 100696064ULL   // codebook    [2048,1024]

// ---------------------------------------------------------------------------
// Kernel 1: fp32 GEMM  S[m][n] = sum_k X[m][k] * C[n][k]
// 128x128 block tile, 8x8 micro-tile per thread, K-panels of 16 in LDS.
// ---------------------------------------------------------------------------
__global__ __launch_bounds__(256) void gemm_kernel(const float* __restrict__ X,
                                                   const float* __restrict__ C,
                                                   float* __restrict__ S) {
    __shared__ float As[16][128];
    __shared__ float Bs[16][128];

    const int tid = threadIdx.x;
    const int tx = tid & 15;        // 0..15 -> column group
    const int ty = tid >> 4;        // 0..15 -> row group
    const int n0 = blockIdx.x * 128;
    const int m0 = blockIdx.y * 128;

    float acc[8][8];
#pragma unroll
    for (int i = 0; i < 8; i++)
#pragma unroll
        for (int j = 0; j < 8; j++) acc[i][j] = 0.0f;

    for (int k0 = 0; k0 < D_DIM; k0 += 16) {
#pragma unroll
        for (int i = 0; i < 2; i++) {
            const int f   = tid + 256 * i;   // float4 slot 0..511
            const int row = f >> 2;          // 0..127
            const int kq  = f & 3;           // which float4 in the row
            const float4 a = *(const float4*)(X + (size_t)(m0 + row) * D_DIM + k0 + kq * 4);
            As[kq * 4 + 0][row] = a.x;
            As[kq * 4 + 1][row] = a.y;
            As[kq * 4 + 2][row] = a.z;
            As[kq * 4 + 3][row] = a.w;
            const float4 b = *(const float4*)(C + (size_t)(n0 + row) * D_DIM + k0 + kq * 4);
            Bs[kq * 4 + 0][row] = b.x;
            Bs[kq * 4 + 1][row] = b.y;
            Bs[kq * 4 + 2][row] = b.z;
            Bs[kq * 4 + 3][row] = b.w;
        }
        __syncthreads();

#pragma unroll
        for (int k = 0; k < 16; k++) {
            const float4 a0 = *(const float4*)&As[k][ty * 8];
            const float4 a1 = *(const float4*)&As[k][ty * 8 + 4];
            const float4 b0 = *(const float4*)&Bs[k][tx * 8];
            const float4 b1 = *(const float4*)&Bs[k][tx * 8 + 4];
            const float a[8] = {a0.x, a0.y, a0.z, a0.w, a1.x, a1.y, a1.z, a1.w};
            const float b[8] = {b0.x, b0.y, b0.z, b0.w, b1.x, b1.y, b1.z, b1.w};
#pragma unroll
            for (int i = 0; i < 8; i++)
#pragma unroll
                for (int j = 0; j < 8; j++) acc[i][j] = fmaf(a[i], b[j], acc[i][j]);
        }
        __syncthreads();
    }

#pragma unroll
    for (int i = 0; i < 8; i++) {
        const size_t row = (size_t)(m0 + ty * 8 + i);
        float4* dst = (float4*)(S + row * K_DIM + n0 + tx * 8);
        dst[0] = make_float4(acc[i][0], acc[i][1], acc[i][2], acc[i][3]);
        dst[1] = make_float4(acc[i][4], acc[i][5], acc[i][6], acc[i][7]);
    }
}

// ---------------------------------------------------------------------------
// (value,index) comparator: "better" = larger value, tie -> smaller index
// (matches np.argmax first-occurrence semantics)
// ---------------------------------------------------------------------------
__device__ __forceinline__ bool better(float av, int ai, float bv, int bi) {
    return av > bv || (av == bv && ai < bi);
}

// ---------------------------------------------------------------------------
// Kernel 2: per-row softmax stats. One wave per row (8 rows/wave sequential,
// 32 rows/block). Produces top-2 candidate indices, accumulates diversity[K]
// and sum of row entropies into workspace.
// ---------------------------------------------------------------------------
__global__ __launch_bounds__(256) void rowstats_kernel(const float* __restrict__ S,
                                                       int2* __restrict__ cand,
                                                       float* __restrict__ div_acc,
                                                       float* __restrict__ hclust_acc) {
    __shared__ float sdiv[K_DIM];
    __shared__ float s_ent;

    const int tid = threadIdx.x;
    for (int k = tid; k < K_DIM; k += 256) sdiv[k] = 0.0f;
    if (tid == 0) s_ent = 0.0f;
    __syncthreads();

    const int lane = tid & 63;
    const int wave = tid >> 6;

    for (int r8 = 0; r8 < 8; r8++) {
        const int row = blockIdx.x * 32 + wave * 8 + r8;
        const float* srow = S + (size_t)row * K_DIM;

        float v[32];
#pragma unroll
        for (int j = 0; j < 32; j++) v[j] = srow[lane + 64 * j];

        // per-lane top-2 (value,index), indices scanned in increasing order
        float v1 = v[0], v2 = -INFINITY;
        int   i1 = lane, i2 = 0x7fffffff;
#pragma unroll
        for (int j = 1; j < 32; j++) {
            const int k = lane + 64 * j;
            const float val = v[j];
            if (val > v1) {                     // k > i1 always, so strict >
                v2 = v1; i2 = i1; v1 = val; i1 = k;
            } else if (val > v2 || (val == v2 && k < i2)) {
                v2 = val; i2 = k;
            }
        }
        // butterfly merge of top-2 lists across 64 lanes
        for (int off = 32; off > 0; off >>= 1) {
            const float ov1 = __shfl_xor(v1, off, 64);
            const int   oi1 = __shfl_xor(i1, off, 64);
            const float ov2 = __shfl_xor(v2, off, 64);
            const int   oi2 = __shfl_xor(i2, off, 64);
            float n1v, n2v; int n1i, n2i;
            if (better(v1, i1, ov1, oi1)) {
                n1v = v1; n1i = i1;
                if (better(v2, i2, ov1, oi1)) { n2v = v2; n2i = i2; }
                else                          { n2v = ov1; n2i = oi1; }
            } else {
                n1v = ov1; n1i = oi1;
                if (better(ov2, oi2, v1, i1)) { n2v = ov2; n2i = oi2; }
                else                          { n2v = v1; n2i = i1; }
            }
            v1 = n1v; i1 = n1i; v2 = n2v; i2 = n2i;
        }

        // softmax pieces: max is v1 (all lanes agree)
        float Z = 0.0f;
#pragma unroll
        for (int j = 0; j < 32; j++) {
            v[j] = __expf(v[j] - v1);
            Z += v[j];
        }
        for (int off = 32; off > 0; off >>= 1) Z += __shfl_xor(Z, off, 64);
        const float invZ = 1.0f / Z;

        float ent = 0.0f;
#pragma unroll
        for (int j = 0; j < 32; j++) {
            const float p = v[j] * invZ;
            ent += p * __log2f(p + 1e-8f);
            atomicAdd(&sdiv[lane + 64 * j], p);
        }
        for (int off = 32; off > 0; off >>= 1) ent += __shfl_xor(ent, off, 64);

        if (lane == 0) {
            cand[row] = make_int2(i1, i2);
            atomicAdd(&s_ent, ent);
        }
    }
    __syncthreads();

    for (int k = tid; k < K_DIM; k += 256) atomicAdd(&div_acc[k], sdiv[k]);
    if (tid == 0) atomicAdd(hclust_acc, s_ent);
}

// ---------------------------------------------------------------------------
// Kernel 2b: fp64 argmax refinement. One wave per row: recompute the two
// candidate dot products in double precision and pick the true winner.
// ---------------------------------------------------------------------------
__global__ __launch_bounds__(256) void refine_kernel(const float* __restrict__ X,
                                                     const float* __restrict__ C,
                                                     const int2* __restrict__ cand,
                                                     float* __restrict__ nn_out) {
    const int tid = threadIdx.x;
    const int lane = tid & 63;
    const int wave = tid >> 6;
    const int row = blockIdx.x * 4 + wave;

    const int2 c2 = cand[row];
    const float* x  = X + (size_t)row * D_DIM;
    const float* ca = C + (size_t)c2.x * D_DIM;
    const float* cb = C + (size_t)c2.y * D_DIM;

    double s1 = 0.0, s2 = 0.0;
#pragma unroll
    for (int q = 0; q < 4; q++) {
        const float4 xv = *(const float4*)(x + lane * 4 + 256 * q);
        const float4 av = *(const float4*)(ca + lane * 4 + 256 * q);
        const float4 bv = *(const float4*)(cb + lane * 4 + 256 * q);
        s1 += (double)xv.x * av.x + (double)xv.y * av.y + (double)xv.z * av.z + (double)xv.w * av.w;
        s2 += (double)xv.x * bv.x + (double)xv.y * bv.y + (double)xv.z * bv.z + (double)xv.w * bv.w;
    }
    for (int off = 32; off > 0; off >>= 1) {
        s1 += __shfl_xor(s1, off, 64);
        s2 += __shfl_xor(s2, off, 64);
    }

    if (lane == 0) {
        int pick;
        if (s1 > s2)      pick = c2.x;
        else if (s2 > s1) pick = c2.y;
        else              pick = min(c2.x, c2.y);   // exact tie -> first index
        nn_out[row] = (float)pick;
    }
}

// ---------------------------------------------------------------------------
// Kernel 3: finalize scalar loss = h_clust - GAMMA * h_diversity
// ---------------------------------------------------------------------------
__global__ __launch_bounds__(256) void finalize_kernel(const float* __restrict__ div_acc,
                                                       const float* __restrict__ hclust_acc,
                                                       float* __restrict__ loss_out) {
    __shared__ float red[256];
    const int tid = threadIdx.x;
    float sum = 0.0f;
    for (int k = tid; k < K_DIM; k += 256) {
        const float d = div_acc[k] * (1.0f / 32768.0f);
        sum += d * __log2f(d + 1e-8f);
    }
    red[tid] = sum;
    __syncthreads();
    for (int s = 128; s > 0; s >>= 1) {
        if (tid < s) red[tid] += red[tid + s];
        __syncthreads();
    }
    if (tid == 0) {
        const float h_clust = -hclust_acc[0] * (1.0f / 32768.0f);
        const float h_div = -red[0];
        loss_out[0] = h_clust - 1.0f * h_div;   // GAMMA = 1
    }
}

// ---------------------------------------------------------------------------
// Kernel 4: broadcast loss scalar into out1 region (67,108,864 floats)
// ---------------------------------------------------------------------------
__global__ __launch_bounds__(256) void fill_kernel(float* __restrict__ out1,
                                                   const float* __restrict__ loss_ptr) {
    const float v = loss_ptr[0];
    const float4 f = make_float4(v, v, v, v);
    float4* o = (float4*)out1;
    const size_t stride = (size_t)gridDim.x * blockDim.x;
    for (size_t i = (size_t)blockIdx.x * blockDim.x + threadIdx.x; i < 16777216ULL; i += stride)
        o[i] = f;
}

// ---------------------------------------------------------------------------
// Kernel 5: quantized = normalize(center(codebook[nn_idx])). One wave per row.
// ---------------------------------------------------------------------------
__global__ __launch_bounds__(256) void quantize_kernel(const float* __restrict__ C,
                                                       const float* __restrict__ nn_f,
                                                       float* __restrict__ out0) {
    const int tid = threadIdx.x;
    const int lane = tid & 63;
    const int wave = tid >> 6;
    const int row = blockIdx.x * 4 + wave;

    const int idx = (int)nn_f[row];
    const float* c = C + (size_t)idx * D_DIM;

    float4 v[4];
    float sum = 0.0f;
#pragma unroll
    for (int q = 0; q < 4; q++) {
        v[q] = *(const float4*)(c + lane * 4 + 256 * q);
        sum += v[q].x + v[q].y + v[q].z + v[q].w;
    }
    for (int off = 32; off > 0; off >>= 1) sum += __shfl_xor(sum, off, 64);
    const float mean = sum * (1.0f / 1024.0f);

    float ss = 0.0f;
#pragma unroll
    for (int q = 0; q < 4; q++) {
        v[q].x -= mean; v[q].y -= mean; v[q].z -= mean; v[q].w -= mean;
        ss += v[q].x * v[q].x + v[q].y * v[q].y + v[q].z * v[q].z + v[q].w * v[q].w;
    }
    for (int off = 32; off > 0; off >>= 1) ss += __shfl_xor(ss, off, 64);
    const float inv = 1.0f / sqrtf(ss);

    float* o = out0 + (size_t)row * D_DIM;
#pragma unroll
    for (int q = 0; q < 4; q++) {
        float4 w = v[q];
        w.x *= inv; w.y *= inv; w.z *= inv; w.w *= inv;
        *(float4*)(o + lane * 4 + 256 * q) = w;
    }
}

// ---------------------------------------------------------------------------
// Kernel 6: codebook passthrough copy (2,097,152 floats)
// ---------------------------------------------------------------------------
__global__ __launch_bounds__(256) void copycb_kernel(const float* __restrict__ C,
                                                     float* __restrict__ out3) {
    const size_t i = (size_t)blockIdx.x * 256 + threadIdx.x;
    if (i < 524288ULL) ((float4*)out3)[i] = ((const float4*)C)[i];
}

// ---------------------------------------------------------------------------
extern "C" void kernel_launch(void* const* d_in, const int* in_sizes, int n_in,
                              void* d_out, int out_size, void* d_ws, size_t ws_size,
                              hipStream_t stream) {
    const float* X = (const float*)d_in[0];   // [16,2048,1024]
    const float* C = (const float*)d_in[1];   // [2048,1024]
    float* out = (float*)d_out;

    float* S = out + OUT1_OFF;                // similarity scratch in out1 region
    float* div_acc = (float*)d_ws;            // [2048]
    float* hclust_acc = div_acc + 2048;       // [1]
    float* loss = div_acc + 2049;             // [1]
    int2* cand = (int2*)(div_acc + 2050);     // [32768] top-2 candidate indices

    // zero diversity + entropy accumulators
    hipMemsetAsync(d_ws, 0, 2050 * sizeof(float), stream);

    // 1) S = X @ C^T
    gemm_kernel<<<dim3(K_DIM / 128, M_TOTAL / 128), 256, 0, stream>>>(X, C, S);

    // 2) per-row softmax stats -> top-2 cand, diversity, entropy sum
    rowstats_kernel<<<M_TOTAL / 32, 256, 0, stream>>>(S, cand, div_acc, hclust_acc);

    // 2b) fp64 argmax refinement -> nn_idx (as float)
    refine_kernel<<<M_TOTAL / 4, 256, 0, stream>>>(X, C, cand, out + OUT2_OFF);

    // 3) scalar loss
    finalize_kernel<<<1, 256, 0, stream>>>(div_acc, hclust_acc, loss);

    // 4) quantized rows (reads nn_idx, doesn't touch out1)
    quantize_kernel<<<M_TOTAL / 4, 256, 0, stream>>>(C, out + OUT2_OFF, out + OUT0_OFF);

    // 5) broadcast loss over out1 (overwrites S scratch)
    fill_kernel<<<8192, 256, 0, stream>>>(out + OUT1_OFF, loss);

    // 6) codebook copy
    copycb_kernel<<<2048, 256, 0, stream>>>(C, out + OUT3_OFF);
}

// Round 3
// 1052.982 us; speedup vs baseline: 2.3131x; 2.3131x over previous
//
#include <hip/hip_runtime.h>
#include <math.h>

// Problem constants
#define M_TOTAL 32768   // B*T = 16*2048
#define D_DIM   1024
#define K_DIM   2048

// d_out flat layout (float32 elements)
#define OUT0_OFF 0ULL           // quantized   [32768,1024]  (scratch until quantize)
#define OUT1_OFF 33554432ULL    // quant_loss  [32768,2048] (S scratch, then loss fill)
#define OUT2_OFF 100663296ULL   // nn_idx      [32768] (written as float)
#define OUT3_OFF 100696064ULL   // codebook    [2048,1024]

typedef _Float16 f16x4 __attribute__((ext_vector_type(4)));
typedef _Float16 f16x8 __attribute__((ext_vector_type(8)));
typedef float    f32x4 __attribute__((ext_vector_type(4)));

// ---------------------------------------------------------------------------
// async 16B global -> LDS (wave-uniform LDS base + lane*16)
// ---------------------------------------------------------------------------
__device__ __forceinline__ void async_copy16(void* lds, const void* g) {
    __builtin_amdgcn_global_load_lds(
        (const __attribute__((address_space(1))) unsigned int*)g,
        (__attribute__((address_space(3))) unsigned int*)lds, 16, 0, 0);
}

// ---------------------------------------------------------------------------
// Kernel 0: codebook fp32 -> (ch, cl) fp16 split.  c = ch + cl + O(2^-22)
// ---------------------------------------------------------------------------
__global__ __launch_bounds__(256) void convcb_kernel(const float* __restrict__ C,
                                                     _Float16* __restrict__ ch,
                                                     _Float16* __restrict__ cl) {
    const int i = blockIdx.x * 256 + threadIdx.x;   // float4 index, 524288 total
    const float4 c = ((const float4*)C)[i];
    f16x4 h, l;
    h.x = (_Float16)c.x; l.x = (_Float16)(c.x - (float)h.x);
    h.y = (_Float16)c.y; l.y = (_Float16)(c.y - (float)h.y);
    h.z = (_Float16)c.z; l.z = (_Float16)(c.z - (float)h.z);
    h.w = (_Float16)c.w; l.w = (_Float16)(c.w - (float)h.w);
    ((f16x4*)ch)[i] = h;
    ((f16x4*)cl)[i] = l;
}

// ---------------------------------------------------------------------------
// Kernel 1: MFMA GEMM  S[m][n] = xh[m]·ch[n] + xh[m]·cl[n]
// 128x128 tile, 4 waves each 64x64 (4x4 of 16x16x32 f16), BK=32.
// A: fp32 load + convert in-register; B: global_load_lds from pre-split fp16.
// ---------------------------------------------------------------------------
__global__ __launch_bounds__(256) void gemm_kernel(const float* __restrict__ X,
                                                   const _Float16* __restrict__ CH,
                                                   const _Float16* __restrict__ CL,
                                                   float* __restrict__ S) {
    __shared__ _Float16 Ah[128 * 32];
    __shared__ _Float16 Bh[128 * 32];
    __shared__ _Float16 Bl[128 * 32];

    const int tid  = threadIdx.x;
    const int lane = tid & 63;
    const int wave = tid >> 6;
    const int n0 = blockIdx.x * 128;
    const int m0 = blockIdx.y * 128;
    const int wm = (wave & 1) * 64;
    const int wn = (wave >> 1) * 64;
    const int fr = lane & 15;    // row within 16x16 tile
    const int fq = lane >> 4;    // k-quad / row-quad

    f32x4 acc[4][4];
#pragma unroll
    for (int mi = 0; mi < 4; mi++)
#pragma unroll
        for (int ni = 0; ni < 4; ni++) {
            acc[mi][ni].x = 0.f; acc[mi][ni].y = 0.f;
            acc[mi][ni].z = 0.f; acc[mi][ni].w = 0.f;
        }

    for (int k0 = 0; k0 < D_DIM; k0 += 32) {
        // ---- B staging: 4 async 1KB issues per wave (2 Bh + 2 Bl) ----
#pragma unroll
        for (int e = 0; e < 2; e++) {
            const int u   = wave * 128 + e * 64 + lane;   // 16B unit 0..511
            const int row = u >> 2;
            const int off = u & 3;
            const size_t gofs = (size_t)(n0 + row) * D_DIM + k0 + off * 8;
            async_copy16((void*)(Bh + (size_t)(wave * 128 + e * 64) * 8), (const void*)(CH + gofs));
            async_copy16((void*)(Bl + (size_t)(wave * 128 + e * 64) * 8), (const void*)(CL + gofs));
        }
        // ---- A staging: fp32 -> fp16 convert, lane-linear LDS writes ----
#pragma unroll
        for (int i = 0; i < 4; i++) {
            const int f = i * 256 + tid;        // float4 unit 0..1023
            const int r = f >> 3;               // row 0..127
            const int q = f & 7;                // float4 within 32-k row
            const float4 a = *(const float4*)(X + (size_t)(m0 + r) * D_DIM + k0 + q * 4);
            f16x4 h;
            h.x = (_Float16)a.x; h.y = (_Float16)a.y;
            h.z = (_Float16)a.z; h.w = (_Float16)a.w;
            *(f16x4*)(Ah + r * 32 + q * 4) = h;
        }
        __syncthreads();

        // ---- fragments + MFMA ----
        f16x8 afrag[4], bhfrag[4], blfrag[4];
#pragma unroll
        for (int t = 0; t < 4; t++) {
            afrag[t]  = *(const f16x8*)(Ah + (wm + t * 16 + fr) * 32 + fq * 8);
            bhfrag[t] = *(const f16x8*)(Bh + (wn + t * 16 + fr) * 32 + fq * 8);
            blfrag[t] = *(const f16x8*)(Bl + (wn + t * 16 + fr) * 32 + fq * 8);
        }
#pragma unroll
        for (int mi = 0; mi < 4; mi++)
#pragma unroll
            for (int ni = 0; ni < 4; ni++) {
                acc[mi][ni] = __builtin_amdgcn_mfma_f32_16x16x32_f16(afrag[mi], bhfrag[ni], acc[mi][ni], 0, 0, 0);
                acc[mi][ni] = __builtin_amdgcn_mfma_f32_16x16x32_f16(afrag[mi], blfrag[ni], acc[mi][ni], 0, 0, 0);
            }
        __syncthreads();
    }

    // ---- epilogue: C/D layout col=lane&15, row=(lane>>4)*4+reg ----
#pragma unroll
    for (int mi = 0; mi < 4; mi++)
#pragma unroll
        for (int r = 0; r < 4; r++) {
            float* dst = S + (size_t)(m0 + wm + mi * 16 + fq * 4 + r) * K_DIM + n0 + wn;
#pragma unroll
            for (int ni = 0; ni < 4; ni++) dst[ni * 16 + fr] = acc[mi][ni][r];
        }
}

// ---------------------------------------------------------------------------
// Kernel 2: per-row stats. One wave per row-octet. Produces candidate lists
// (all k within MARGIN of row max), diversity (register-accumulated), entropy.
// ---------------------------------------------------------------------------
#define MARGIN 0.125f
__global__ __launch_bounds__(256) void rowstats_kernel(const float* __restrict__ S,
                                                       int* __restrict__ cnt,
                                                       int* __restrict__ cand,
                                                       float* __restrict__ div_acc,
                                                       float* __restrict__ hclust_acc) {
    __shared__ float sdiv[K_DIM];
    const int tid = threadIdx.x;
    for (int k = tid; k < K_DIM; k += 256) sdiv[k] = 0.0f;
    __syncthreads();

    const int lane = tid & 63;
    const int wave = tid >> 6;

    float dreg[32];
#pragma unroll
    for (int j = 0; j < 32; j++) dreg[j] = 0.0f;
    float ent_acc = 0.0f;

    for (int r8 = 0; r8 < 8; r8++) {
        const int row = blockIdx.x * 32 + wave * 8 + r8;
        const float* srow = S + (size_t)row * K_DIM;

        float v[32];
#pragma unroll
        for (int j = 0; j < 32; j++) v[j] = srow[lane + 64 * j];

        float m = v[0];
#pragma unroll
        for (int j = 1; j < 32; j++) m = fmaxf(m, v[j]);
        for (int off = 32; off > 0; off >>= 1) m = fmaxf(m, __shfl_xor(m, off, 64));

        // candidate extraction: everything within MARGIN of the max
        const float thresh = m - MARGIN;
#pragma unroll
        for (int j = 0; j < 32; j++) {
            if (v[j] > thresh) {
                const int slot = atomicAdd(&cnt[row], 1);
                if (slot < 8) cand[row * 8 + slot] = lane + 64 * j;
            }
        }

        // softmax pieces
        float Z = 0.0f;
#pragma unroll
        for (int j = 0; j < 32; j++) {
            v[j] = __expf(v[j] - m);
            Z += v[j];
        }
        for (int off = 32; off > 0; off >>= 1) Z += __shfl_xor(Z, off, 64);
        const float invZ = 1.0f / Z;

#pragma unroll
        for (int j = 0; j < 32; j++) {
            const float p = v[j] * invZ;
            dreg[j] += p;                          // diversity: same k across rows
            ent_acc += p * __log2f(p + 1e-8f);     // per-lane entropy partial
        }
    }

    // merge per-lane diversity into block LDS (4 waves -> 2-deep atomics)
#pragma unroll
    for (int j = 0; j < 32; j++) atomicAdd(&sdiv[lane + 64 * j], dreg[j]);
    for (int off = 32; off > 0; off >>= 1) ent_acc += __shfl_xor(ent_acc, off, 64);
    if (lane == 0) atomicAdd(hclust_acc, ent_acc);
    __syncthreads();

    for (int k = tid; k < K_DIM; k += 256) atomicAdd(&div_acc[k], sdiv[k]);
}

// ---------------------------------------------------------------------------
// Kernel 2b: fp64 argmax over candidate list. One wave per row.
// ---------------------------------------------------------------------------
__global__ __launch_bounds__(256) void refine_kernel(const float* __restrict__ X,
                                                     const float* __restrict__ C,
                                                     const int* __restrict__ cnt,
                                                     const int* __restrict__ cand,
                                                     float* __restrict__ nn_out) {
    const int tid = threadIdx.x;
    const int lane = tid & 63;
    const int wave = tid >> 6;
    const int row = blockIdx.x * 4 + wave;

    const int n = min(cnt[row], 8);
    const float* x = X + (size_t)row * D_DIM;

    float4 xv[4];
#pragma unroll
    for (int q = 0; q < 4; q++) xv[q] = *(const float4*)(x + lane * 4 + 256 * q);

    double bestv = -1.0e300;
    int besti = 0x7fffffff;
    for (int c = 0; c < n; c++) {
        const int idx = cand[row * 8 + c];
        const float* cb = C + (size_t)idx * D_DIM;
        double s = 0.0;
#pragma unroll
        for (int q = 0; q < 4; q++) {
            const float4 cv = *(const float4*)(cb + lane * 4 + 256 * q);
            s += (double)xv[q].x * cv.x + (double)xv[q].y * cv.y +
                 (double)xv[q].z * cv.z + (double)xv[q].w * cv.w;
        }
        for (int off = 32; off > 0; off >>= 1) s += __shfl_xor(s, off, 64);
        if (s > bestv || (s == bestv && idx < besti)) { bestv = s; besti = idx; }
    }
    if (lane == 0) nn_out[row] = (float)besti;
}

// ---------------------------------------------------------------------------
// Kernel 3: finalize scalar loss = h_clust - GAMMA * h_diversity
// ---------------------------------------------------------------------------
__global__ __launch_bounds__(256) void finalize_kernel(const float* __restrict__ div_acc,
                                                       const float* __restrict__ hclust_acc,
                                                       float* __restrict__ loss_out) {
    __shared__ float red[256];
    const int tid = threadIdx.x;
    float sum = 0.0f;
    for (int k = tid; k < K_DIM; k += 256) {
        const float d = div_acc[k] * (1.0f / 32768.0f);
        sum += d * __log2f(d + 1e-8f);
    }
    red[tid] = sum;
    __syncthreads();
    for (int s = 128; s > 0; s >>= 1) {
        if (tid < s) red[tid] += red[tid + s];
        __syncthreads();
    }
    if (tid == 0) {
        const float h_clust = -hclust_acc[0] * (1.0f / 32768.0f);
        const float h_div = -red[0];
        loss_out[0] = h_clust - 1.0f * h_div;   // GAMMA = 1
    }
}

// ---------------------------------------------------------------------------
// Kernel 4: broadcast loss scalar into out1 region (67,108,864 floats)
// ---------------------------------------------------------------------------
__global__ __launch_bounds__(256) void fill_kernel(float* __restrict__ out1,
                                                   const float* __restrict__ loss_ptr) {
    const float v = loss_ptr[0];
    const float4 f = make_float4(v, v, v, v);
    float4* o = (float4*)out1;
    const size_t stride = (size_t)gridDim.x * blockDim.x;
    for (size_t i = (size_t)blockIdx.x * blockDim.x + threadIdx.x; i < 16777216ULL; i += stride)
        o[i] = f;
}

// ---------------------------------------------------------------------------
// Kernel 5: quantized = normalize(center(codebook[nn_idx])). One wave per row.
// ---------------------------------------------------------------------------
__global__ __launch_bounds__(256) void quantize_kernel(const float* __restrict__ C,
                                                       const float* __restrict__ nn_f,
                                                       float* __restrict__ out0) {
    const int tid = threadIdx.x;
    const int lane = tid & 63;
    const int wave = tid >> 6;
    const int row = blockIdx.x * 4 + wave;

    const int idx = (int)nn_f[row];
    const float* c = C + (size_t)idx * D_DIM;

    float4 v[4];
    float sum = 0.0f;
#pragma unroll
    for (int q = 0; q < 4; q++) {
        v[q] = *(const float4*)(c + lane * 4 + 256 * q);
        sum += v[q].x + v[q].y + v[q].z + v[q].w;
    }
    for (int off = 32; off > 0; off >>= 1) sum += __shfl_xor(sum, off, 64);
    const float mean = sum * (1.0f / 1024.0f);

    float ss = 0.0f;
#pragma unroll
    for (int q = 0; q < 4; q++) {
        v[q].x -= mean; v[q].y -= mean; v[q].z -= mean; v[q].w -= mean;
        ss += v[q].x * v[q].x + v[q].y * v[q].y + v[q].z * v[q].z + v[q].w * v[q].w;
    }
    for (int off = 32; off > 0; off >>= 1) ss += __shfl_xor(ss, off, 64);
    const float inv = 1.0f / sqrtf(ss);

    float* o = out0 + (size_t)row * D_DIM;
#pragma unroll
    for (int q = 0; q < 4; q++) {
        float4 w = v[q];
        w.x *= inv; w.y *= inv; w.z *= inv; w.w *= inv;
        *(float4*)(o + lane * 4 + 256 * q) = w;
    }
}

// ---------------------------------------------------------------------------
// Kernel 6: codebook passthrough copy (2,097,152 floats)
// ---------------------------------------------------------------------------
__global__ __launch_bounds__(256) void copycb_kernel(const float* __restrict__ C,
                                                     float* __restrict__ out3) {
    const size_t i = (size_t)blockIdx.x * 256 + threadIdx.x;
    if (i < 524288ULL) ((float4*)out3)[i] = ((const float4*)C)[i];
}

// ---------------------------------------------------------------------------
extern "C" void kernel_launch(void* const* d_in, const int* in_sizes, int n_in,
                              void* d_out, int out_size, void* d_ws, size_t ws_size,
                              hipStream_t stream) {
    const float* X = (const float*)d_in[0];   // [16,2048,1024]
    const float* C = (const float*)d_in[1];   // [2048,1024]
    float* out = (float*)d_out;

    // scratch lives in the out0 region (free until quantize_kernel runs)
    char* scratch = (char*)d_out;
    _Float16* CH  = (_Float16*)(scratch);                 // 4 MB
    _Float16* CL  = (_Float16*)(scratch + (4 << 20));     // 4 MB
    int* cand     = (int*)(scratch + (8 << 20));          // 1 MB  [32768][8]
    int* cnt      = (int*)(scratch + (9 << 20));          // 128 KB
    float* div_acc   = (float*)(scratch + (9 << 20) + (128 << 10));  // 8 KB
    float* hclust    = div_acc + 2048;
    float* loss      = div_acc + 2049;

    float* S = out + OUT1_OFF;                // similarity scratch in out1 region

    // zero cnt + div + hclust (+loss)
    hipMemsetAsync(scratch + (9 << 20), 0, (128 << 10) + 8192 + 16, stream);

    // 0) codebook fp16 split
    convcb_kernel<<<2048, 256, 0, stream>>>(C, CH, CL);

    // 1) S = xh·ch + xh·cl  (fp16 MFMA)
    gemm_kernel<<<dim3(K_DIM / 128, M_TOTAL / 128), 256, 0, stream>>>(X, CH, CL, S);

    // 2) per-row stats -> candidates, diversity, entropy sum
    rowstats_kernel<<<M_TOTAL / 32, 256, 0, stream>>>(S, cnt, cand, div_acc, hclust);

    // 2b) fp64 argmax refinement -> nn_idx (as float)
    refine_kernel<<<M_TOTAL / 4, 256, 0, stream>>>(X, C, cnt, cand, out + OUT2_OFF);

    // 3) scalar loss
    finalize_kernel<<<1, 256, 0, stream>>>(div_acc, hclust, loss);

    // 4) broadcast loss over out1 (overwrites S scratch; S no longer needed)
    fill_kernel<<<8192, 256, 0, stream>>>(out + OUT1_OFF, loss);

    // 5) quantized rows (overwrites out0 scratch; loss already consumed)
    quantize_kernel<<<M_TOTAL / 4, 256, 0, stream>>>(C, out + OUT2_OFF, out + OUT0_OFF);

    // 6) codebook copy
    copycb_kernel<<<2048, 256, 0, stream>>>(C, out + OUT3_OFF);
}